// Round 16
// baseline (187.153 us; speedup 1.0000x reference)
//
#include <hip/hip_runtime.h>

#define EPSB 1e-5f
#define B_ 4
#define N_ 256
#define H_ 16
#define D_ 5
#define E_ 4096
#define M_PAIR (B_*N_*N_)   // 262144

typedef __attribute__((ext_vector_type(8))) short short8;
typedef __attribute__((ext_vector_type(4))) float f32x4;

// ---- stats slot offsets (floats) in ws ----
enum {
  SO_ANGX = 0,   // ang sum, ang sq
  SO_CENX = 2,   // cen sum, cen sq
  SO_MOMA = 16,  // P, N, Pq, Nq for angle dx
  SO_MOMC = 24,  // same for centroid
  SO_FC   = 992, SO_FCQ   = 1008,
  SO_ET1  = 1024, SO_ET1Q = 1040,
  SO_ET2  = 1056, SO_ET2Q = 1072,
  SO_EL1  = 1088, SO_EL1Q = 1104,
  SO_EL2  = 1120, SO_EL2Q = 1136,
  SO_EV1  = 1152, SO_EV1Q = 1168,
  SO_EV2  = 1184, SO_EV2Q = 1200,
  SO_G1   = 1216, SO_G1Q  = 1280,
  SO_G2   = 1344, SO_G2Q  = 1360,
  SP_C1   = 2048,
  SP_C2   = SP_C1 + 32*512,   // 18432
  SP_C3   = SP_C2 + 32*512,   // 34816
  PSTATS_END = SP_C3 + 32*512 // 51200
};

// ---- buffer offsets (floats) ----
static constexpr size_t F_Y13  = 51200;                // y1 bf16 [E][20][64] / y3 bf16 [E][20][256]
static constexpr size_t F_Y2   = F_Y13 + 10485760;     // y2 bf16 [E][20][128]
static constexpr size_t F_POOL = F_Y2 + 5242880;       // slack
static constexpr size_t F_FCB  = F_POOL + 1048576;     // E*16 (fc out, later z2 of edgeconv)
static constexpr size_t F_EF   = F_FCB + 65536;        // slack
static constexpr size_t F_PROJ = F_EF + 65536;         // 1024*16
static constexpr size_t F_Z1EC = F_PROJ + 16384;       // z1ec [64][E]  (o-major)
static constexpr size_t F_Z2T  = F_Z1EC + 262144;      // 3 x E*16 raw z2
static constexpr size_t F_G    = F_Z2T + 196608;       // [4*1025][5][16]
static constexpr size_t F_WT2  = F_G + 328000;         // 128*192 bf16
static constexpr size_t F_WT3  = F_WT2 + 12288;        // 256*384 bf16

__device__ __forceinline__ float waveSum(float v){
  #pragma unroll
  for(int o=32;o;o>>=1) v += __shfl_down(v,o);
  return v;
}

__device__ __forceinline__ ushort f2bf(float f){
  uint u = __float_as_uint(f);
  uint r = (u + 0x7FFF + ((u>>16)&1)) >> 16;
  return (ushort)r;
}
__device__ __forceinline__ float bf2f(ushort u){
  return __uint_as_float(((uint)u)<<16);
}

// ---------------- zero the stats region ----------------
__global__ __launch_bounds__(256) void k_zero(float* __restrict__ ws){
  int t=blockIdx.x*256+threadIdx.x;
  if(t<PSTATS_END) ws[t]=0.0f;
}

// block = 256 threads. Reduce 16 sums + 16 sumsqs, atomicAdd to ws.
__device__ __forceinline__ void red32_atomic(float* ws, int so, int soq, float* s, float* q){
  __shared__ float red[4][32];
  int tid=threadIdx.x, lane=tid&63, wid=tid>>6;
  #pragma unroll
  for(int k=0;k<16;k++){
    float rs=waveSum(s[k]), rq=waveSum(q[k]);
    if(lane==0){ red[wid][k]=rs; red[wid][16+k]=rq; }
  }
  __syncthreads();
  if(tid<32){
    float t=red[0][tid]+red[1][tid]+red[2][tid]+red[3][tid];
    atomicAdd(&ws[tid<16 ? so+tid : soq+(tid-16)], t);
  }
}

// ================= k_conv1: [E,12,20] -> y1 bf16 [E][20][64], 4 edges/block ======
__global__ __launch_bounds__(256) void k_conv1(const float* __restrict__ ed,
    const float* __restrict__ w, float* __restrict__ ws){
  __shared__ float wsh[64*37];
  __shared__ float xs[4*12*20];
  __shared__ float reds[256], redq[256];
  int tid=threadIdx.x;
  for(int i=tid;i<2304;i+=256){ int o=i/36, r=i%36; wsh[o*37+r]=w[i]; }
  int e0=blockIdx.x*4;
  for(int i=tid;i<960;i+=256){
    int e=i/240, r=i%240, l=r/12, c=r%12;
    xs[(e*12+c)*20+l]=ed[(size_t)(e0+e)*240+r];
  }
  __syncthreads();
  int o=tid&63, eg=tid>>6;       // wave = edge
  ushort* y1=(ushort*)(ws+F_Y13);
  float ssum=0, ssq=0;
  {
    int e=eg;
    float acc[20];
    #pragma unroll
    for(int l=0;l<20;l++) acc[l]=0;
    for(int c=0;c<12;c++){
      float w0=wsh[o*37+c*3], w1=wsh[o*37+c*3+1], w2=wsh[o*37+c*3+2];
      const float* xr=xs+(e*12+c)*20;
      #pragma unroll
      for(int l=0;l<20;l++){
        acc[l]=fmaf(w1,xr[l],acc[l]);
        if(l>0)  acc[l]=fmaf(w0,xr[l-1],acc[l]);
        if(l<19) acc[l]=fmaf(w2,xr[l+1],acc[l]);
      }
    }
    size_t base=((size_t)(e0+e)*20)*64;
    #pragma unroll
    for(int l=0;l<20;l++){
      y1[base+(size_t)l*64+o]=f2bf(acc[l]);
      ssum+=acc[l]; ssq+=acc[l]*acc[l];
    }
  }
  reds[eg*64+o]=ssum; redq[eg*64+o]=ssq;
  __syncthreads();
  int g=blockIdx.x&31;
  if(tid<64){
    atomicAdd(&ws[SP_C1+g*512+tid], reds[tid]+reds[64+tid]+reds[128+tid]+reds[192+tid]);
  } else if(tid<128){
    int oo=tid-64;
    atomicAdd(&ws[SP_C1+g*512+256+oo], redq[oo]+redq[64+oo]+redq[128+oo]+redq[192+oo]);
  }
}

// ================= k_misc: wprep + proj + scalar + sml1 =================

__device__ void dev_wprep(int bid, const float* __restrict__ c2w,
    const float* __restrict__ c3w, ushort* __restrict__ wt2, ushort* __restrict__ wt3){
  int t = bid*256 + threadIdx.x;
  if(t < 128*192){
    int idx=t;
    int j=idx&7, lane=(idx>>3)&63, ks=(idx>>9)%6, ct=idx/3072;
    int l16=lane&15, lhi=lane>>4;
    int o=ct*16+l16, tap=ks/2, c=(ks%2)*32+lhi*8+j;
    wt2[idx]=f2bf(c2w[(o*64+c)*3+tap]);
  } else {
    int idx=t-128*192;
    if(idx<256*384){
      int j=idx&7, lane=(idx>>3)&63, ks=(idx>>9)%12, ct=idx/6144;
      int l16=lane&15, lhi=lane>>4;
      int o=ct*16+l16, tap=ks/4, c=(ks%4)*32+lhi*8+j;
      wt3[idx]=f2bf(c3w[(o*128+c)*3+tap]);
    }
  }
}

__device__ void dev_proj(int bid, const float* __restrict__ nf,
    const float* __restrict__ Wp, float* __restrict__ ws, char* pool){
  float* wps=(float*)pool;            // [16][260] padded
  int tid=threadIdx.x;
  for(int i=tid;i<4096;i+=256){ wps[(i>>8)*260+(i&255)]=Wp[i]; }
  __syncthreads();
  int t=bid*256+tid;
  int v=t>>4, h=t&15;
  const float4* row=(const float4*)(nf+(size_t)v*256);
  const float4* wr=(const float4*)(wps+h*260);
  float z=0;
  #pragma unroll 8
  for(int c=0;c<64;c++){
    float4 a=row[c], b=wr[c];
    z+=a.x*b.x+a.y*b.y+a.z*b.z+a.w*b.w;
  }
  ws[F_PROJ+t]=z;
}

__device__ void dev_scalar(int bid, const float* __restrict__ ang,
    const float* __restrict__ cen, float* __restrict__ st){
  int tid = bid*256 + threadIdx.x;
  float sa=0, qa=0, sc=0, qc=0;
  for(int i=tid; i<M_PAIR; i += 256*256){
    float a=ang[i], c=cen[i];
    sa+=a; qa+=a*a; sc+=c; qc+=c*c;
  }
  __shared__ float red[4][4];
  int lane=threadIdx.x&63, wid=threadIdx.x>>6;
  sa=waveSum(sa); qa=waveSum(qa); sc=waveSum(sc); qc=waveSum(qc);
  if(lane==0){ red[wid][0]=sa; red[wid][1]=qa; red[wid][2]=sc; red[wid][3]=qc; }
  __syncthreads();
  if(threadIdx.x<4){
    float t=red[0][threadIdx.x]+red[1][threadIdx.x]+red[2][threadIdx.x]+red[3][threadIdx.x];
    atomicAdd(&st[threadIdx.x], t);
  }
}

template<int DIM>
__device__ void dev_sml1(const float* __restrict__ x,
    const float* __restrict__ W1, float* __restrict__ ws, int so, int soq, int bid){
  __shared__ float w1s[176];
  int tid=threadIdx.x;
  if(tid<16*DIM) w1s[tid]=W1[tid];
  __syncthreads();
  int e=bid*256+tid;
  float xv[DIM];
  #pragma unroll
  for(int j=0;j<DIM;j++) xv[j]=x[(size_t)e*DIM+j];
  float s[16], q[16];
  #pragma unroll
  for(int k=0;k<16;k++){
    float z=0;
    #pragma unroll
    for(int j=0;j<DIM;j++) z+=w1s[k*DIM+j]*xv[j];
    s[k]=z; q[k]=z*z;
  }
  red32_atomic(ws, so, soq, s, q);
}

// blocks: [0,480) wprep | [480,544) proj | [544,800) scalar | [800,848) sml1
__global__ __launch_bounds__(256) void k_misc(
    const float* __restrict__ c2w, const float* __restrict__ c3w,
    const float* __restrict__ nf, const float* __restrict__ Wp,
    const float* __restrict__ ang, const float* __restrict__ cen,
    const float* __restrict__ et, const float* __restrict__ el, const float* __restrict__ ev,
    const float* __restrict__ etW1, const float* __restrict__ elW1, const float* __restrict__ evW1,
    float* __restrict__ ws){
  __shared__ char pool[16640];
  int bx=blockIdx.x;
  if(bx<480)       dev_wprep(bx, c2w, c3w, (ushort*)(ws+F_WT2), (ushort*)(ws+F_WT3));
  else if(bx<544)  dev_proj(bx-480, nf, Wp, ws, pool);
  else if(bx<800)  dev_scalar(bx-544, ang, cen, ws);
  else {
    int bid=bx-800;
    int g=bid>>4, b2=bid&15;
    if(g==0)      dev_sml1<11>(et,etW1,ws,SO_ET1,SO_ET1Q,b2);
    else if(g==1) dev_sml1<1> (el,elW1,ws,SO_EL1,SO_EL1Q,b2);
    else          dev_sml1<3> (ev,evW1,ws,SO_EV1,SO_EV1Q,b2);
  }
}

// ================= k_stats2 =================

__device__ void dev_mom2(int bid, const float* __restrict__ x, float* __restrict__ st,
    int soX, int mo){
  int tid=threadIdx.x;
  float mu = st[soX]*(1.0f/262144.0f);
  float P=0,N=0,Pq=0,Nq=0;
  for(int i=bid*256+tid; i<M_PAIR; i+=32*256){
    float dx=x[i]-mu;
    if(dx>0){ P+=dx; Pq+=dx*dx; } else { N+=dx; Nq+=dx*dx; }
  }
  __shared__ float red[4][4];
  int lane=tid&63, wid=tid>>6;
  P=waveSum(P); N=waveSum(N); Pq=waveSum(Pq); Nq=waveSum(Nq);
  if(lane==0){ red[wid][0]=P; red[wid][1]=N; red[wid][2]=Pq; red[wid][3]=Nq; }
  __syncthreads();
  if(tid<4){
    float t=red[0][tid]+red[1][tid]+red[2][tid]+red[3][tid];
    atomicAdd(&st[mo+tid], t);
  }
}

template<int DIM>
__device__ void dev_sml2(const float* __restrict__ x,
    const float* __restrict__ W1, const float* __restrict__ W2,
    float* __restrict__ ws, int so1, int so1q, int so2, int so2q,
    float* __restrict__ z2out, int bid){
  __shared__ float w1s[176];
  __shared__ float w2s[256];
  __shared__ float mi[16][2];
  int tid=threadIdx.x;
  if(tid<16*DIM) w1s[tid]=W1[tid];
  w2s[tid]=W2[tid];
  if(tid<16){
    float m=ws[so1+tid]*(1.0f/4096.0f);
    float v=ws[so1q+tid]*(1.0f/4096.0f)-m*m; if(v<0)v=0;
    mi[tid][0]=m; mi[tid][1]=rsqrtf(v+EPSB);
  }
  __syncthreads();
  int e=bid*256+tid;
  float xv[DIM];
  #pragma unroll
  for(int j=0;j<DIM;j++) xv[j]=x[(size_t)e*DIM+j];
  float h1[16];
  #pragma unroll
  for(int h=0;h<16;h++){
    float z=0;
    #pragma unroll
    for(int j=0;j<DIM;j++) z+=w1s[h*DIM+j]*xv[j];
    z=(z-mi[h][0])*mi[h][1];
    h1[h]=z>0?z:0;
  }
  float s[16], q[16];
  #pragma unroll
  for(int k=0;k<16;k++){
    float z=0;
    #pragma unroll
    for(int h=0;h<16;h++) z+=w2s[k*16+h]*h1[h];
    z2out[(size_t)e*16+k]=z;
    s[k]=z; q[k]=z*z;
  }
  red32_atomic(ws, so2, so2q, s, q);
}

// blocks: [0,32) mom ang | [32,64) mom cen | [64,112) sml2
__global__ __launch_bounds__(256) void k_stats2(
    const float* __restrict__ ang, const float* __restrict__ cen,
    const float* __restrict__ et, const float* __restrict__ el, const float* __restrict__ ev,
    const float* __restrict__ etW1, const float* __restrict__ etW2,
    const float* __restrict__ elW1, const float* __restrict__ elW2,
    const float* __restrict__ evW1, const float* __restrict__ evW2,
    float* __restrict__ ws){
  int bx=blockIdx.x;
  if(bx<32)       dev_mom2(bx, ang, ws, SO_ANGX, SO_MOMA);
  else if(bx<64)  dev_mom2(bx-32, cen, ws, SO_CENX, SO_MOMC);
  else {
    int bid=bx-64;
    int g=bid>>4, b2=bid&15;
    if(g==0)      dev_sml2<11>(et,etW1,etW2,ws,SO_ET1,SO_ET1Q,SO_ET2,SO_ET2Q,ws+F_Z2T,b2);
    else if(g==1) dev_sml2<1> (el,elW1,elW2,ws,SO_EL1,SO_EL1Q,SO_EL2,SO_EL2Q,ws+F_Z2T+65536,b2);
    else          dev_sml2<3> (ev,evW1,evW2,ws,SO_EV1,SO_EV1Q,SO_EV2,SO_EV2Q,ws+F_Z2T+131072,b2);
  }
}

// ------- MFMA conv: NSPLIT=2, B tri-buffered (depth-2 prefetch), LDS epilogue -------
template<int CIN, int OUT, int EPB, int NSPLIT>
__global__ __launch_bounds__(256) void k_convmf(
    const ushort* __restrict__ yin, const ushort* __restrict__ wt,
    ushort* __restrict__ yout, float* __restrict__ ws,
    int spIn, int spOut)
{
  constexpr int K = CIN*3;
  constexpr int KSTEPS = K/32;
  constexpr int M = EPB*20;                  // 80
  constexpr int ROWT = M/16;                 // 5
  constexpr int WCOLT = OUT/(64*NSPLIT);
  constexpr int COLS = OUT/NSPLIT;
  constexpr int OST = COLS + 8;              // padded LDS out-tile stride (ushorts)
  constexpr int ROWS = EPB*22;
  constexpr int RB = CIN*2;
  constexpr uint SWZ = RB/16 - 1;
  constexpr int XS_ELEMS = (ROWS*CIN > M*OST) ? ROWS*CIN : M*OST;
  __shared__ ushort xs[XS_ELEMS];
  __shared__ float mi[CIN][2];
  int tid = threadIdx.x;
  int bx = blockIdx.x;
  int eblk = bx / NSPLIT, split = bx % NSPLIT;
  int lane = tid&63, wid = tid>>6;
  int l16 = lane&15, lhi = lane>>4;
  int colbase = (split*4 + wid) * (COLS/4);
  int lcolbase = wid * (COLS/4);

  const ushort* wp[WCOLT];
  #pragma unroll
  for(int n=0;n<WCOLT;n++)
    wp[n] = wt + ((size_t)(colbase/16 + n)*KSTEPS)*512 + (size_t)lane*8;

  // BN params: sum 32 partial groups
  for(int c=tid; c<CIN; c+=256){
    float s=0,q=0;
    #pragma unroll
    for(int g=0;g<32;g++){ s+=ws[spIn+g*512+c]; q+=ws[spIn+g*512+256+c]; }
    float m=s*(1.0f/81920.0f);
    float v=q*(1.0f/81920.0f)-m*m; if(v<0)v=0;
    mi[c][0]=m; mi[c][1]=rsqrtf(v+EPSB);
  }
  uint* xs32 = (uint*)xs;
  for(int i=tid; i<EPB*2*(CIN/2); i+=256){
    int e=i/(CIN), r=i%(CIN); int lp = (r < CIN/2)? 0:21; int cw = r%(CIN/2);
    xs32[(e*22+lp)*(CIN/2)+cw]=0;
  }
  __syncthreads();
  int e0 = eblk*EPB;
  const ushort* src = yin + (size_t)e0*20*CIN;
  for(int i=tid; i<EPB*20*(CIN/8); i+=256){
    int c8 = i%(CIN/8); int rl = i/(CIN/8);
    int c = c8*8;
    short8 v = *(const short8*)(src + (size_t)rl*CIN + c);
    uint pk[4];
    #pragma unroll
    for(int jj=0;jj<4;jj++){
      float f0 = bf2f((ushort)v[jj*2]);
      float f1 = bf2f((ushort)v[jj*2+1]);
      f0=(f0-mi[c+jj*2  ][0])*mi[c+jj*2  ][1]; f0= f0>=0?f0:0.01f*f0;
      f1=(f1-mi[c+jj*2+1][0])*mi[c+jj*2+1][1]; f1= f1>=0?f1:0.01f*f1;
      pk[jj] = (uint)f2bf(f0) | ((uint)f2bf(f1)<<16);
    }
    int e = rl/20, l=rl%20;
    int row = e*22 + l + 1;
    uint byteoff = (uint)row*RB + (((uint)c*2) ^ (uint)((row&SWZ)<<4));
    *(uint4*)((char*)xs + byteoff) = make_uint4(pk[0],pk[1],pk[2],pk[3]);
  }
  __syncthreads();

  f32x4 acc[ROWT][WCOLT];
  #pragma unroll
  for(int m=0;m<ROWT;m++)
    #pragma unroll
    for(int n=0;n<WCOLT;n++) acc[m][n]=(f32x4){0,0,0,0};
  int rowc[ROWT];
  #pragma unroll
  for(int m=0;m<ROWT;m++){ int r=m*16+l16; rowc[m]=(r/20)*22 + (r%20); }

  short8 aF[2][ROWT], bF[3][WCOLT];

#define LOADA(ksv, sl) { \
    int t_=(ksv)/(CIN/32); int c0_=((ksv)%(CIN/32))*32 + lhi*8; \
    _Pragma("unroll") \
    for(int m=0;m<ROWT;m++){ \
      int row_=rowc[m]+t_; \
      uint off_=(uint)row_*RB + (((uint)c0_*2) ^ (uint)((row_&SWZ)<<4)); \
      aF[sl][m]=*(const short8*)((char*)xs+off_); } }

#define LOADB(ksv, sl) { \
    _Pragma("unroll") \
    for(int n=0;n<WCOLT;n++) bF[sl][n]=*(const short8*)(wp[n] + (size_t)(ksv)*512); }

  LOADA(0, 0); LOADB(0, 0); LOADB(1, 1);
  #pragma unroll
  for(int ks=0; ks<KSTEPS; ks++){
    if(ks+1<KSTEPS) LOADA(ks+1, (ks+1)&1);
    if(ks+2<KSTEPS) LOADB(ks+2, (ks+2)%3);
    #pragma unroll
    for(int m=0;m<ROWT;m++)
      #pragma unroll
      for(int n=0;n<WCOLT;n++)
        acc[m][n]=__builtin_amdgcn_mfma_f32_16x16x32_bf16(aF[ks&1][m],bF[ks%3][n],acc[m][n],0,0,0);
  }
#undef LOADA
#undef LOADB

  int g=bx&31;
  #pragma unroll
  for(int n=0;n<WCOLT;n++){
    float s=0,q=0;
    #pragma unroll
    for(int m=0;m<ROWT;m++)
      #pragma unroll
      for(int j=0;j<4;j++){ float a=acc[m][n][j]; s+=a; q+=a*a; }
    s += __shfl_xor(s,16); s += __shfl_xor(s,32);
    q += __shfl_xor(q,16); q += __shfl_xor(q,32);
    if(lhi==0){
      int o = colbase+n*16+l16;
      atomicAdd(&ws[spOut+g*512+o], s);
      atomicAdd(&ws[spOut+g*512+256+o], q);
    }
  }

  // epilogue: stage bf16 out-tile in LDS (reuse xs), coalesced uint4 copy-out
  __syncthreads();
  #pragma unroll
  for(int m=0;m<ROWT;m++)
    #pragma unroll
    for(int j=0;j<4;j++){
      int R = m*16 + lhi*4 + j;
      #pragma unroll
      for(int n=0;n<WCOLT;n++)
        xs[(size_t)R*OST + lcolbase + n*16 + l16] = f2bf(acc[m][n][j]);
    }
  __syncthreads();
  ushort* dst = yout + (size_t)eblk*M*OUT + (size_t)split*COLS;
  for(int idx=tid; idx<M*(COLS/8); idx+=256){
    int row = idx/(COLS/8), c8 = idx%(COLS/8);
    uint4 v = *(const uint4*)&xs[(size_t)row*OST + c8*8];
    *(uint4*)&dst[(size_t)row*OUT + c8*8] = v;
  }
}

// -------- fused pool+fc (C3 stats from partials) --------
__global__ __launch_bounds__(256) void k_poolfc(const float* __restrict__ fcw, float* __restrict__ ws){
  __shared__ float ps[16][260];
  __shared__ float red[4][32];
  __shared__ float mo[256][2];
  int tid=threadIdx.x;
  {
    float s=0,q=0;
    #pragma unroll
    for(int g=0;g<32;g++){ s+=ws[SP_C3+g*512+tid]; q+=ws[SP_C3+g*512+256+tid]; }
    float m=s*(1.0f/81920.0f);
    float v=q*(1.0f/81920.0f)-m*m; if(v<0)v=0;
    mo[tid][0]=m; mo[tid][1]=rsqrtf(v+EPSB);
  }
  __syncthreads();
  int e0=blockIdx.x*16;
  const ushort* y3=(const ushort*)(ws+F_Y13);
  float m=mo[tid][0], inv=mo[tid][1];
  for(int el=0;el<16;el++){
    const ushort* row=y3+((size_t)(e0+el)*20)*256+tid;
    float s=0;
    #pragma unroll
    for(int l=0;l<20;l++){
      float x=(bf2f(row[(size_t)l*256])-m)*inv;
      s += x>=0.f? x : 0.01f*x;
    }
    ps[el][tid]=s*(1.0f/20.0f);
  }
  __syncthreads();
  int e=tid>>4, h=tid&15;
  const float* wr=fcw+(size_t)h*256;
  float z=0;
  for(int c=0;c<256;c++) z+=ps[e][c]*wr[c];
  ws[F_FCB+(size_t)(e0+e)*16+h]=z;
  float s=z, q=z*z;
  #pragma unroll
  for(int o=16;o<64;o<<=1){ s+=__shfl_down(s,o); q+=__shfl_down(q,o); }
  int lane=tid&63, wid=tid>>6;
  if(lane<16){ red[wid][lane]=s; red[wid][16+lane]=q; }
  __syncthreads();
  if(tid<32){
    float v=red[0][tid]+red[1][tid]+red[2][tid]+red[3][tid];
    atomicAdd(&ws[tid<16? SO_FC+tid : SO_FCQ+(tid-16)], v);
  }
}

// -------- fused ef + edgeconv layer1: grid 128, 32 edges/block --------
__device__ __constant__ int EF_BASES[4][2] = {
  {SO_ET2,SO_ET2Q},{SO_EL2,SO_EL2Q},{SO_EV2,SO_EV2Q},{SO_FC,SO_FCQ}
};

__global__ __launch_bounds__(256) void k_aggef(const int* __restrict__ src, const int* __restrict__ dst,
    const float* __restrict__ ecW1, float* __restrict__ ws){
  __shared__ float w1s[64*17];
  __shared__ float mi[4][16][2];
  __shared__ float aLDS[32][17];
  __shared__ float zLDS[64][33];
  __shared__ float reds[4][64], redq[4][64];
  int tid=threadIdx.x;
  for(int i=tid;i<1024;i+=256) w1s[(i>>4)*17+(i&15)]=ecW1[i];
  if(tid<64){
    int g=tid>>4, h=tid&15;
    float m=ws[EF_BASES[g][0]+h]*(1.0f/4096.0f);
    float v=ws[EF_BASES[g][1]+h]*(1.0f/4096.0f)-m*m; if(v<0)v=0;
    mi[g][h][0]=m; mi[g][h][1]=rsqrtf(v+EPSB);
  }
  __syncthreads();
  int e0=blockIdx.x*32;
  for(int it=tid; it<32*16; it+=256){
    int el=it>>4, h=it&15;
    int e=e0+el;
    float z=ws[F_FCB+(size_t)e*16+h];
    float a=(z-mi[3][h][0])*mi[3][h][1];
    #pragma unroll
    for(int g=0;g<3;g++){
      float z2=ws[F_Z2T+(size_t)g*65536+(size_t)e*16+h];
      float r=(z2-mi[g][h][0])*mi[g][h][1];
      a+= r>0?r:0;
    }
    int s=src[e], d=dst[e];
    a+=ws[F_PROJ+(size_t)s*16+h]+ws[F_PROJ+(size_t)d*16+h];
    aLDS[el][h]=a;
  }
  __syncthreads();
  int o=tid&63, elq=tid>>6;
  float s=0,q=0;
  #pragma unroll
  for(int j=0;j<8;j++){
    int el=elq*8+j;
    float z=0;
    #pragma unroll
    for(int h=0;h<16;h++) z+=w1s[o*17+h]*aLDS[el][h];
    zLDS[o][el]=z;
    s+=z; q+=z*z;
  }
  reds[elq][o]=s; redq[elq][o]=q;
  __syncthreads();
  for(int idx=tid; idx<2048; idx+=256){
    int oo=idx>>5, el=idx&31;
    ws[F_Z1EC+(size_t)oo*E_+e0+el]=zLDS[oo][el];
  }
  if(tid<64){
    atomicAdd(&ws[SO_G1+tid], reds[0][tid]+reds[1][tid]+reds[2][tid]+reds[3][tid]);
  } else if(tid<128){
    int oo=tid-64;
    atomicAdd(&ws[SO_G1Q+oo], redq[0][oo]+redq[1][oo]+redq[2][oo]+redq[3][oo]);
  }
}

// ---------------- edgeconv layer2 ----------------
__global__ __launch_bounds__(256) void k_ec2(const float* __restrict__ ecW2, float* __restrict__ ws){
  __shared__ float w2s[1024];
  __shared__ float mi[64][2];
  int tid=threadIdx.x;
  for(int i=tid;i<1024;i+=256) w2s[i]=ecW2[i];
  if(tid<64){
    float m=ws[SO_G1+tid]*(1.0f/4096.0f);
    float v=ws[SO_G1Q+tid]*(1.0f/4096.0f)-m*m; if(v<0)v=0;
    mi[tid][0]=m; mi[tid][1]=rsqrtf(v+EPSB);
  }
  __syncthreads();
  int el=tid&63, kq=tid>>6;
  int e=blockIdx.x*64+el;
  float acc[4]={0,0,0,0};
  #pragma unroll 8
  for(int o=0;o<64;o++){
    float z=ws[F_Z1EC+(size_t)o*E_+e];
    float h=(z-mi[o][0])*mi[o][1];
    h=h>0?h:0;
    #pragma unroll
    for(int j=0;j<4;j++) acc[j]+=w2s[(kq*4+j)*64+o]*h;
  }
  #pragma unroll
  for(int j=0;j<4;j++) ws[F_FCB+(size_t)e*16+kq*4+j]=acc[j];
  #pragma unroll
  for(int j=0;j<4;j++){
    float rs=waveSum(acc[j]);
    float rq=waveSum(acc[j]*acc[j]);
    if(el==0){
      atomicAdd(&ws[SO_G2+kq*4+j], rs);
      atomicAdd(&ws[SO_G2Q+kq*4+j], rq);
    }
  }
}

// -------- edge_feature + per-hop projection --------
__global__ __launch_bounds__(256) void k_ef2g(const float* __restrict__ edisw, float* __restrict__ ws){
  __shared__ float wd[1280];
  __shared__ float mi[16][2];
  int tid=threadIdx.x;
  for(int i=tid;i<1280;i+=256) wd[i]=edisw[i];
  if(tid<16){
    float m=ws[SO_G2+tid]*(1.0f/4096.0f);
    float va=ws[SO_G2Q+tid]*(1.0f/4096.0f)-m*m; if(va<0)va=0;
    mi[tid][0]=m; mi[tid][1]=rsqrtf(va+EPSB);
  }
  __syncthreads();
  int t=blockIdx.x*256+tid;
  if(t>=4*1025*5) return;
  int bp=t/5, d=t%5;
  int b=bp/1025, pos=bp%1025;
  float ef[16];
  if(pos<1024){
    int e=b*1024+pos;
    #pragma unroll
    for(int k=0;k<16;k++){
      float z=ws[F_FCB+(size_t)e*16+k];
      float v=(z-mi[k][0])*mi[k][1];
      ef[k]= v>0?v:0;
    }
  } else {
    #pragma unroll
    for(int k=0;k<16;k++) ef[k]=0;
  }
  float* g=ws+F_G+(size_t)bp*80+d*16;
  const float* wdd=wd+d*256;
  #pragma unroll
  for(int k=0;k<16;k++){
    float s=0;
    #pragma unroll
    for(int h=0;h<16;h++) s+=ef[h]*wdd[h*16+k];
    g[k]=s;
  }
}

// ---------------- main per-pair kernel ----------------
__global__ __launch_bounds__(256) void k_pair(const float* __restrict__ ab,
    const int* __restrict__ sd, const float* __restrict__ ang, const float* __restrict__ cen,
    const int* __restrict__ ep, const float* __restrict__ sdemb,
    const float* __restrict__ angW1, const float* __restrict__ angW2,
    const float* __restrict__ cenW1, const float* __restrict__ cenW2,
    const float* __restrict__ ws, float* __restrict__ out){
  __shared__ float cpa[16],cma[16],m2a[16],i2a[16];
  __shared__ float cpc[16],cmc[16],m2c[16],i2c[16];
  __shared__ float mv[4];
  int tid=threadIdx.x;
  if(tid==0){
    float s=ws[SO_ANGX], q=ws[SO_ANGX+1];
    float mu=s*(1.0f/262144.0f);
    float v=q*(1.0f/262144.0f)-mu*mu; if(v<0)v=0;
    mv[0]=mu; mv[1]=v;
    s=ws[SO_CENX]; q=ws[SO_CENX+1];
    mu=s*(1.0f/262144.0f);
    v=q*(1.0f/262144.0f)-mu*mu; if(v<0)v=0;
    mv[2]=mu; mv[3]=v;
  }
  __syncthreads();
  if(tid<32){
    int k=tid&15; bool isC = tid>=16;
    const float* W1=isC?cenW1:angW1; const float* W2=isC?cenW2:angW2;
    float var=isC?mv[3]:mv[1];
    float cp=0, cm=0;
    for(int h=0;h<16;h++){
      float w=W1[h];
      float A=w*rsqrtf(var*w*w+EPSB);
      float wk=W2[k*16+h];
      if(A>0) cp+=wk*A; else cm+=wk*A;
    }
    int mo = isC? SO_MOMC : SO_MOMA;
    float P=ws[mo], N=ws[mo+1], Pq=ws[mo+2], Nq=ws[mo+3];
    float mean=(cp*P+cm*N)*(1.0f/262144.0f);
    float e2=(cp*cp*Pq+cm*cm*Nq)*(1.0f/262144.0f);
    float v2=e2-mean*mean; if(v2<0)v2=0;
    float iv=rsqrtf(v2+EPSB);
    if(!isC){ cpa[k]=cp; cma[k]=cm; m2a[k]=mean; i2a[k]=iv; }
    else    { cpc[k]=cp; cmc[k]=cm; m2c[k]=mean; i2c[k]=iv; }
  }
  __syncthreads();
  int t=blockIdx.x*256+tid;            // b,i,j
  int b=t>>16, rem=t&65535, i=rem>>8, j=rem&255;
  int sdv=sd[t];
  float xa=ang[t], xc0=cen[t];
  float acc[16];
  const float* se=sdemb+(size_t)sdv*16;
  #pragma unroll
  for(int k=0;k<16;k++) acc[k]=se[k];
  { // angle (closed form)
    float dx=xa-mv[0];
    bool pos=dx>0.f;
    #pragma unroll
    for(int k=0;k<16;k++){
      float z=dx*(pos?cpa[k]:cma[k]);
      float r=(z-m2a[k])*i2a[k];
      acc[k]+= r>0?r:0;
    }
  }
  { // centroid (closed form)
    float dx=xc0-mv[2];
    bool pos=dx>0.f;
    #pragma unroll
    for(int k=0;k<16;k++){
      float z=dx*(pos?cpc[k]:cmc[k]);
      float r=(z-m2c[k])*i2c[k];
      acc[k]+= r>0?r:0;
    }
  }
  { // multi-hop edge bias via precomputed G
    int sdm = sdv==0 ? 1 : sdv;
    if(sdm>1) sdm-=1;
    if(sdm>5) sdm=5;
    float inv=1.0f/((float)sdm+1e-6f);
    float eb[16];
    #pragma unroll
    for(int k=0;k<16;k++) eb[k]=0;
    const float* G=ws+F_G;
    #pragma unroll
    for(int d=0;d<5;d++){
      int idx=ep[(size_t)t*5+d];
      const float4* g=(const float4*)(G+(size_t)(b*1025+idx)*80+d*16);
      float4 g0=g[0], g1=g[1], g2=g[2], g3=g[3];
      eb[0]+=g0.x; eb[1]+=g0.y; eb[2]+=g0.z; eb[3]+=g0.w;
      eb[4]+=g1.x; eb[5]+=g1.y; eb[6]+=g1.z; eb[7]+=g1.w;
      eb[8]+=g2.x; eb[9]+=g2.y; eb[10]+=g2.z; eb[11]+=g2.w;
      eb[12]+=g3.x; eb[13]+=g3.y; eb[14]+=g3.z; eb[15]+=g3.w;
    }
    #pragma unroll
    for(int k=0;k<16;k++) acc[k]+=eb[k]*inv;
  }
  float base2=2.0f*ab[(size_t)b*66049+(size_t)(i+1)*257+(j+1)];
  #pragma unroll
  for(int k=0;k<16;k++)
    out[(((size_t)b*16+k)*257+(i+1))*257+(j+1)]=acc[k]+base2;
}

// ---------------- borders ----------------
__global__ __launch_bounds__(256) void k_border(const float* __restrict__ ab,
    const float* __restrict__ virt, float* __restrict__ out){
  int t=blockIdx.x*256+threadIdx.x;
  if(t>=4*16*513) return;
  int idx=t%513, bh=t/513;
  int b=bh>>4, h=bh&15;
  float v=virt[h];
  if(idx<257){
    out[(((size_t)b*16+h)*257)*257+idx]=2.0f*ab[(size_t)b*66049+idx]+v;
  } else {
    int p=idx-256;
    out[(((size_t)b*16+h)*257+p)*257]=2.0f*ab[(size_t)b*66049+(size_t)p*257]+v;
  }
}

extern "C" void kernel_launch(void* const* d_in, const int* in_sizes, int n_in,
                              void* d_out, int out_size, void* d_ws, size_t ws_size,
                              hipStream_t stream) {
  const float* ab    =(const float*)d_in[0];
  const int*   sdist =(const int*)  d_in[1];
  const float* ang   =(const float*)d_in[2];
  const float* cen   =(const float*)d_in[3];
  const int*   ep    =(const int*)  d_in[4];
  const float* edata =(const float*)d_in[5];
  const float* etype =(const float*)d_in[6];
  const float* elen  =(const float*)d_in[7];
  const float* econv =(const float*)d_in[8];
  const int*   src   =(const int*)  d_in[10];
  const int*   dst   =(const int*)  d_in[11];
  const float* nf    =(const float*)d_in[12];
  const float* sdemb =(const float*)d_in[13];
  const float* virt  =(const float*)d_in[14];
  const float* angW1 =(const float*)d_in[15];
  const float* angW2 =(const float*)d_in[16];
  const float* cenW1 =(const float*)d_in[17];
  const float* cenW2 =(const float*)d_in[18];
  const float* etW1  =(const float*)d_in[19];
  const float* etW2  =(const float*)d_in[20];
  const float* elW1  =(const float*)d_in[21];
  const float* elW2  =(const float*)d_in[22];
  const float* evW1  =(const float*)d_in[23];
  const float* evW2  =(const float*)d_in[24];
  const float* c1w   =(const float*)d_in[25];
  const float* c2w   =(const float*)d_in[26];
  const float* c3w   =(const float*)d_in[27];
  const float* fcw   =(const float*)d_in[28];
  const float* edisw =(const float*)d_in[29];
  const float* ecWp  =(const float*)d_in[30];
  const float* ecW1  =(const float*)d_in[31];
  const float* ecW2  =(const float*)d_in[32];
  float* ws=(float*)d_ws;
  float* out=(float*)d_out;

  k_zero<<<(PSTATS_END+255)/256,256,0,stream>>>(ws);

  k_conv1<<<1024,256,0,stream>>>(edata,c1w,ws);
  k_misc<<<848,256,0,stream>>>(c2w,c3w,nf,ecWp,ang,cen,
                               etype,elen,econv,etW1,elW1,evW1,ws);
  k_stats2<<<112,256,0,stream>>>(ang,cen,etype,elen,econv,
                                 etW1,etW2,elW1,elW2,evW1,evW2,ws);

  k_convmf<64,128,4,2><<<2048,256,0,stream>>>((const ushort*)(ws+F_Y13),(const ushort*)(ws+F_WT2),
                                              (ushort*)(ws+F_Y2),ws,SP_C1,SP_C2);
  k_convmf<128,256,4,2><<<2048,256,0,stream>>>((const ushort*)(ws+F_Y2),(const ushort*)(ws+F_WT3),
                                               (ushort*)(ws+F_Y13),ws,SP_C2,SP_C3);
  k_poolfc<<<256,256,0,stream>>>(fcw,ws);

  k_aggef<<<128,256,0,stream>>>(src,dst,ecW1,ws);
  k_ec2<<<64,256,0,stream>>>(ecW2,ws);
  k_ef2g<<<81,256,0,stream>>>(edisw,ws);

  k_pair<<<1024,256,0,stream>>>(ab,sdist,ang,cen,ep,sdemb,angW1,angW2,cenW1,cenW2,ws,out);
  k_border<<<129,256,0,stream>>>(ab,virt,out);
}

// Round 17
// 176.497 us; speedup vs baseline: 1.0604x; 1.0604x over previous
//
#include <hip/hip_runtime.h>

#define EPSB 1e-5f
#define B_ 4
#define N_ 256
#define H_ 16
#define D_ 5
#define E_ 4096
#define M_PAIR (B_*N_*N_)   // 262144

typedef __attribute__((ext_vector_type(8))) short short8;
typedef __attribute__((ext_vector_type(4))) float f32x4;

// ---- stats slot offsets (floats) in ws ----
enum {
  SO_ANGX = 0,   // ang sum, ang sq
  SO_CENX = 2,   // cen sum, cen sq
  SO_MOMA = 16,  // P, N, Pq, Nq for angle dx
  SO_MOMC = 24,  // same for centroid
  SO_FC   = 992, SO_FCQ   = 1008,
  SO_ET1  = 1024, SO_ET1Q = 1040,
  SO_ET2  = 1056, SO_ET2Q = 1072,
  SO_EL1  = 1088, SO_EL1Q = 1104,
  SO_EL2  = 1120, SO_EL2Q = 1136,
  SO_EV1  = 1152, SO_EV1Q = 1168,
  SO_EV2  = 1184, SO_EV2Q = 1200,
  SO_G1   = 1216, SO_G1Q  = 1280,
  SO_G2   = 1344, SO_G2Q  = 1360,
  SP_C1   = 2048,
  SP_C2   = SP_C1 + 32*512,   // 18432
  SP_C3   = SP_C2 + 32*512,   // 34816
  PSTATS_END = SP_C3 + 32*512 // 51200
};

// ---- buffer offsets (floats) ----
static constexpr size_t F_Y13  = 51200;                // y1 bf16 [E][20][64] / y3 bf16 [E][20][256]
static constexpr size_t F_Y2   = F_Y13 + 10485760;     // y2 bf16 [E][20][128]
static constexpr size_t F_POOL = F_Y2 + 5242880;       // slack
static constexpr size_t F_FCB  = F_POOL + 1048576;     // E*16 (fc out, later z2 of edgeconv)
static constexpr size_t F_EF   = F_FCB + 65536;        // slack
static constexpr size_t F_PROJ = F_EF + 65536;         // 1024*16
static constexpr size_t F_Z1EC = F_PROJ + 16384;       // z1ec [64][E]  (o-major)
static constexpr size_t F_Z2T  = F_Z1EC + 262144;      // 3 x E*16 raw z2
static constexpr size_t F_G    = F_Z2T + 196608;       // [4*1025][5][16]
static constexpr size_t F_WT2  = F_G + 328000;         // 128*192 bf16
static constexpr size_t F_WT3  = F_WT2 + 12288;        // 256*384 bf16

__device__ __forceinline__ float waveSum(float v){
  #pragma unroll
  for(int o=32;o;o>>=1) v += __shfl_down(v,o);
  return v;
}

__device__ __forceinline__ ushort f2bf(float f){
  uint u = __float_as_uint(f);
  uint r = (u + 0x7FFF + ((u>>16)&1)) >> 16;
  return (ushort)r;
}
__device__ __forceinline__ float bf2f(ushort u){
  return __uint_as_float(((uint)u)<<16);
}

// ---------------- zero the stats region ----------------
__global__ __launch_bounds__(256) void k_zero(float* __restrict__ ws){
  int t=blockIdx.x*256+threadIdx.x;
  if(t<PSTATS_END) ws[t]=0.0f;
}

// block = 256 threads. Reduce 16 sums + 16 sumsqs, atomicAdd to ws.
__device__ __forceinline__ void red32_atomic(float* ws, int so, int soq, float* s, float* q){
  __shared__ float red[4][32];
  int tid=threadIdx.x, lane=tid&63, wid=tid>>6;
  #pragma unroll
  for(int k=0;k<16;k++){
    float rs=waveSum(s[k]), rq=waveSum(q[k]);
    if(lane==0){ red[wid][k]=rs; red[wid][16+k]=rq; }
  }
  __syncthreads();
  if(tid<32){
    float t=red[0][tid]+red[1][tid]+red[2][tid]+red[3][tid];
    atomicAdd(&ws[tid<16 ? so+tid : soq+(tid-16)], t);
  }
}

// ================= k_conv1: [E,12,20] -> y1 bf16 [E][20][64], 8 edges/block ======
__global__ __launch_bounds__(256) void k_conv1(const float* __restrict__ ed,
    const float* __restrict__ w, float* __restrict__ ws){
  __shared__ float wsh[64*37];
  __shared__ float xs[8*12*20];
  __shared__ float reds[256], redq[256];
  int tid=threadIdx.x;
  for(int i=tid;i<2304;i+=256){ int o=i/36, r=i%36; wsh[o*37+r]=w[i]; }
  int e0=blockIdx.x*8;
  for(int i=tid;i<1920;i+=256){
    int e=i/240, r=i%240, l=r/12, c=r%12;
    xs[(e*12+c)*20+l]=ed[(size_t)(e0+e)*240+r];
  }
  __syncthreads();
  int o=tid&63, eg=tid>>6;
  ushort* y1=(ushort*)(ws+F_Y13);
  float ssum=0, ssq=0;
  for(int ee=0;ee<2;ee++){
    int e=eg*2+ee;
    float acc[20];
    #pragma unroll
    for(int l=0;l<20;l++) acc[l]=0;
    for(int c=0;c<12;c++){
      float w0=wsh[o*37+c*3], w1=wsh[o*37+c*3+1], w2=wsh[o*37+c*3+2];
      const float* xr=xs+(e*12+c)*20;
      #pragma unroll
      for(int l=0;l<20;l++){
        acc[l]=fmaf(w1,xr[l],acc[l]);
        if(l>0)  acc[l]=fmaf(w0,xr[l-1],acc[l]);
        if(l<19) acc[l]=fmaf(w2,xr[l+1],acc[l]);
      }
    }
    size_t base=((size_t)(e0+e)*20)*64;
    #pragma unroll
    for(int l=0;l<20;l++){
      y1[base+(size_t)l*64+o]=f2bf(acc[l]);
      ssum+=acc[l]; ssq+=acc[l]*acc[l];
    }
  }
  reds[eg*64+o]=ssum; redq[eg*64+o]=ssq;
  __syncthreads();
  int g=blockIdx.x&31;
  if(tid<64){
    atomicAdd(&ws[SP_C1+g*512+tid], reds[tid]+reds[64+tid]+reds[128+tid]+reds[192+tid]);
  } else if(tid<128){
    int oo=tid-64;
    atomicAdd(&ws[SP_C1+g*512+256+oo], redq[oo]+redq[64+oo]+redq[128+oo]+redq[192+oo]);
  }
}

// ================= k_misc: wprep + proj + scalar + sml1 =================

__device__ void dev_wprep(int bid, const float* __restrict__ c2w,
    const float* __restrict__ c3w, ushort* __restrict__ wt2, ushort* __restrict__ wt3){
  int t = bid*256 + threadIdx.x;
  if(t < 128*192){
    int idx=t;
    int j=idx&7, lane=(idx>>3)&63, ks=(idx>>9)%6, ct=idx/3072;
    int l16=lane&15, lhi=lane>>4;
    int o=ct*16+l16, tap=ks/2, c=(ks%2)*32+lhi*8+j;
    wt2[idx]=f2bf(c2w[(o*64+c)*3+tap]);
  } else {
    int idx=t-128*192;
    if(idx<256*384){
      int j=idx&7, lane=(idx>>3)&63, ks=(idx>>9)%12, ct=idx/6144;
      int l16=lane&15, lhi=lane>>4;
      int o=ct*16+l16, tap=ks/4, c=(ks%4)*32+lhi*8+j;
      wt3[idx]=f2bf(c3w[(o*128+c)*3+tap]);
    }
  }
}

__device__ void dev_proj(int bid, const float* __restrict__ nf,
    const float* __restrict__ Wp, float* __restrict__ ws, char* pool){
  float* wps=(float*)pool;            // [16][260] padded
  int tid=threadIdx.x;
  for(int i=tid;i<4096;i+=256){ wps[(i>>8)*260+(i&255)]=Wp[i]; }
  __syncthreads();
  int t=bid*256+tid;
  int v=t>>4, h=t&15;
  const float4* row=(const float4*)(nf+(size_t)v*256);
  const float4* wr=(const float4*)(wps+h*260);
  float z=0;
  #pragma unroll 8
  for(int c=0;c<64;c++){
    float4 a=row[c], b=wr[c];
    z+=a.x*b.x+a.y*b.y+a.z*b.z+a.w*b.w;
  }
  ws[F_PROJ+t]=z;
}

__device__ void dev_scalar(int bid, const float* __restrict__ ang,
    const float* __restrict__ cen, float* __restrict__ st){
  int tid = bid*256 + threadIdx.x;
  float sa=0, qa=0, sc=0, qc=0;
  for(int i=tid; i<M_PAIR; i += 256*256){
    float a=ang[i], c=cen[i];
    sa+=a; qa+=a*a; sc+=c; qc+=c*c;
  }
  __shared__ float red[4][4];
  int lane=threadIdx.x&63, wid=threadIdx.x>>6;
  sa=waveSum(sa); qa=waveSum(qa); sc=waveSum(sc); qc=waveSum(qc);
  if(lane==0){ red[wid][0]=sa; red[wid][1]=qa; red[wid][2]=sc; red[wid][3]=qc; }
  __syncthreads();
  if(threadIdx.x<4){
    float t=red[0][threadIdx.x]+red[1][threadIdx.x]+red[2][threadIdx.x]+red[3][threadIdx.x];
    atomicAdd(&st[threadIdx.x], t);
  }
}

template<int DIM>
__device__ void dev_sml1(const float* __restrict__ x,
    const float* __restrict__ W1, float* __restrict__ ws, int so, int soq, int bid){
  __shared__ float w1s[176];
  int tid=threadIdx.x;
  if(tid<16*DIM) w1s[tid]=W1[tid];
  __syncthreads();
  int e=bid*256+tid;
  float xv[DIM];
  #pragma unroll
  for(int j=0;j<DIM;j++) xv[j]=x[(size_t)e*DIM+j];
  float s[16], q[16];
  #pragma unroll
  for(int k=0;k<16;k++){
    float z=0;
    #pragma unroll
    for(int j=0;j<DIM;j++) z+=w1s[k*DIM+j]*xv[j];
    s[k]=z; q[k]=z*z;
  }
  red32_atomic(ws, so, soq, s, q);
}

// blocks: [0,480) wprep | [480,544) proj | [544,800) scalar | [800,848) sml1
__global__ __launch_bounds__(256) void k_misc(
    const float* __restrict__ c2w, const float* __restrict__ c3w,
    const float* __restrict__ nf, const float* __restrict__ Wp,
    const float* __restrict__ ang, const float* __restrict__ cen,
    const float* __restrict__ et, const float* __restrict__ el, const float* __restrict__ ev,
    const float* __restrict__ etW1, const float* __restrict__ elW1, const float* __restrict__ evW1,
    float* __restrict__ ws){
  __shared__ char pool[16640];
  int bx=blockIdx.x;
  if(bx<480)       dev_wprep(bx, c2w, c3w, (ushort*)(ws+F_WT2), (ushort*)(ws+F_WT3));
  else if(bx<544)  dev_proj(bx-480, nf, Wp, ws, pool);
  else if(bx<800)  dev_scalar(bx-544, ang, cen, ws);
  else {
    int bid=bx-800;
    int g=bid>>4, b2=bid&15;
    if(g==0)      dev_sml1<11>(et,etW1,ws,SO_ET1,SO_ET1Q,b2);
    else if(g==1) dev_sml1<1> (el,elW1,ws,SO_EL1,SO_EL1Q,b2);
    else          dev_sml1<3> (ev,evW1,ws,SO_EV1,SO_EV1Q,b2);
  }
}

// ================= k_stats2 =================

__device__ void dev_mom2(int bid, const float* __restrict__ x, float* __restrict__ st,
    int soX, int mo){
  int tid=threadIdx.x;
  float mu = st[soX]*(1.0f/262144.0f);
  float P=0,N=0,Pq=0,Nq=0;
  for(int i=bid*256+tid; i<M_PAIR; i+=32*256){
    float dx=x[i]-mu;
    if(dx>0){ P+=dx; Pq+=dx*dx; } else { N+=dx; Nq+=dx*dx; }
  }
  __shared__ float red[4][4];
  int lane=tid&63, wid=tid>>6;
  P=waveSum(P); N=waveSum(N); Pq=waveSum(Pq); Nq=waveSum(Nq);
  if(lane==0){ red[wid][0]=P; red[wid][1]=N; red[wid][2]=Pq; red[wid][3]=Nq; }
  __syncthreads();
  if(tid<4){
    float t=red[0][tid]+red[1][tid]+red[2][tid]+red[3][tid];
    atomicAdd(&st[mo+tid], t);
  }
}

template<int DIM>
__device__ void dev_sml2(const float* __restrict__ x,
    const float* __restrict__ W1, const float* __restrict__ W2,
    float* __restrict__ ws, int so1, int so1q, int so2, int so2q,
    float* __restrict__ z2out, int bid){
  __shared__ float w1s[176];
  __shared__ float w2s[256];
  __shared__ float mi[16][2];
  int tid=threadIdx.x;
  if(tid<16*DIM) w1s[tid]=W1[tid];
  w2s[tid]=W2[tid];
  if(tid<16){
    float m=ws[so1+tid]*(1.0f/4096.0f);
    float v=ws[so1q+tid]*(1.0f/4096.0f)-m*m; if(v<0)v=0;
    mi[tid][0]=m; mi[tid][1]=rsqrtf(v+EPSB);
  }
  __syncthreads();
  int e=bid*256+tid;
  float xv[DIM];
  #pragma unroll
  for(int j=0;j<DIM;j++) xv[j]=x[(size_t)e*DIM+j];
  float h1[16];
  #pragma unroll
  for(int h=0;h<16;h++){
    float z=0;
    #pragma unroll
    for(int j=0;j<DIM;j++) z+=w1s[h*DIM+j]*xv[j];
    z=(z-mi[h][0])*mi[h][1];
    h1[h]=z>0?z:0;
  }
  float s[16], q[16];
  #pragma unroll
  for(int k=0;k<16;k++){
    float z=0;
    #pragma unroll
    for(int h=0;h<16;h++) z+=w2s[k*16+h]*h1[h];
    z2out[(size_t)e*16+k]=z;
    s[k]=z; q[k]=z*z;
  }
  red32_atomic(ws, so2, so2q, s, q);
}

// blocks: [0,32) mom ang | [32,64) mom cen | [64,112) sml2
__global__ __launch_bounds__(256) void k_stats2(
    const float* __restrict__ ang, const float* __restrict__ cen,
    const float* __restrict__ et, const float* __restrict__ el, const float* __restrict__ ev,
    const float* __restrict__ etW1, const float* __restrict__ etW2,
    const float* __restrict__ elW1, const float* __restrict__ elW2,
    const float* __restrict__ evW1, const float* __restrict__ evW2,
    float* __restrict__ ws){
  int bx=blockIdx.x;
  if(bx<32)       dev_mom2(bx, ang, ws, SO_ANGX, SO_MOMA);
  else if(bx<64)  dev_mom2(bx-32, cen, ws, SO_CENX, SO_MOMC);
  else {
    int bid=bx-64;
    int g=bid>>4, b2=bid&15;
    if(g==0)      dev_sml2<11>(et,etW1,etW2,ws,SO_ET1,SO_ET1Q,SO_ET2,SO_ET2Q,ws+F_Z2T,b2);
    else if(g==1) dev_sml2<1> (el,elW1,elW2,ws,SO_EL1,SO_EL1Q,SO_EL2,SO_EL2Q,ws+F_Z2T+65536,b2);
    else          dev_sml2<3> (ev,evW1,evW2,ws,SO_EV1,SO_EV1Q,SO_EV2,SO_EV2Q,ws+F_Z2T+131072,b2);
  }
}

// ------- MFMA conv: NSPLIT=2, B tri-buffered, LDS epilogue -------
template<int CIN, int OUT, int EPB, int NSPLIT>
__global__ __launch_bounds__(256) void k_convmf(
    const ushort* __restrict__ yin, const ushort* __restrict__ wt,
    ushort* __restrict__ yout, float* __restrict__ ws,
    int spIn, int spOut)
{
  constexpr int K = CIN*3;
  constexpr int KSTEPS = K/32;
  constexpr int M = EPB*20;                  // 80
  constexpr int ROWT = M/16;                 // 5
  constexpr int WCOLT = OUT/(64*NSPLIT);
  constexpr int COLS = OUT/NSPLIT;
  constexpr int OST = COLS + 8;              // padded LDS out-tile stride (ushorts)
  constexpr int ROWS = EPB*22;
  constexpr int RB = CIN*2;
  constexpr uint SWZ = RB/16 - 1;
  constexpr int XS_ELEMS = (ROWS*CIN > M*OST) ? ROWS*CIN : M*OST;
  __shared__ ushort xs[XS_ELEMS];
  __shared__ float mi[CIN][2];
  int tid = threadIdx.x;
  int bx = blockIdx.x;
  int eblk = bx / NSPLIT, split = bx % NSPLIT;
  int lane = tid&63, wid = tid>>6;
  int l16 = lane&15, lhi = lane>>4;
  int colbase = (split*4 + wid) * (COLS/4);
  int lcolbase = wid * (COLS/4);

  const ushort* wp[WCOLT];
  #pragma unroll
  for(int n=0;n<WCOLT;n++)
    wp[n] = wt + ((size_t)(colbase/16 + n)*KSTEPS)*512 + (size_t)lane*8;

  // BN params: sum 32 partial groups
  for(int c=tid; c<CIN; c+=256){
    float s=0,q=0;
    #pragma unroll
    for(int g=0;g<32;g++){ s+=ws[spIn+g*512+c]; q+=ws[spIn+g*512+256+c]; }
    float m=s*(1.0f/81920.0f);
    float v=q*(1.0f/81920.0f)-m*m; if(v<0)v=0;
    mi[c][0]=m; mi[c][1]=rsqrtf(v+EPSB);
  }
  uint* xs32 = (uint*)xs;
  for(int i=tid; i<EPB*2*(CIN/2); i+=256){
    int e=i/(CIN), r=i%(CIN); int lp = (r < CIN/2)? 0:21; int cw = r%(CIN/2);
    xs32[(e*22+lp)*(CIN/2)+cw]=0;
  }
  __syncthreads();
  int e0 = eblk*EPB;
  const ushort* src = yin + (size_t)e0*20*CIN;
  for(int i=tid; i<EPB*20*(CIN/8); i+=256){
    int c8 = i%(CIN/8); int rl = i/(CIN/8);
    int c = c8*8;
    short8 v = *(const short8*)(src + (size_t)rl*CIN + c);
    uint pk[4];
    #pragma unroll
    for(int jj=0;jj<4;jj++){
      float f0 = bf2f((ushort)v[jj*2]);
      float f1 = bf2f((ushort)v[jj*2+1]);
      f0=(f0-mi[c+jj*2  ][0])*mi[c+jj*2  ][1]; f0= f0>=0?f0:0.01f*f0;
      f1=(f1-mi[c+jj*2+1][0])*mi[c+jj*2+1][1]; f1= f1>=0?f1:0.01f*f1;
      pk[jj] = (uint)f2bf(f0) | ((uint)f2bf(f1)<<16);
    }
    int e = rl/20, l=rl%20;
    int row = e*22 + l + 1;
    uint byteoff = (uint)row*RB + (((uint)c*2) ^ (uint)((row&SWZ)<<4));
    *(uint4*)((char*)xs + byteoff) = make_uint4(pk[0],pk[1],pk[2],pk[3]);
  }
  __syncthreads();

  f32x4 acc[ROWT][WCOLT];
  #pragma unroll
  for(int m=0;m<ROWT;m++)
    #pragma unroll
    for(int n=0;n<WCOLT;n++) acc[m][n]=(f32x4){0,0,0,0};
  int rowc[ROWT];
  #pragma unroll
  for(int m=0;m<ROWT;m++){ int r=m*16+l16; rowc[m]=(r/20)*22 + (r%20); }

  short8 aF[2][ROWT], bF[3][WCOLT];

#define LOADA(ksv, sl) { \
    int t_=(ksv)/(CIN/32); int c0_=((ksv)%(CIN/32))*32 + lhi*8; \
    _Pragma("unroll") \
    for(int m=0;m<ROWT;m++){ \
      int row_=rowc[m]+t_; \
      uint off_=(uint)row_*RB + (((uint)c0_*2) ^ (uint)((row_&SWZ)<<4)); \
      aF[sl][m]=*(const short8*)((char*)xs+off_); } }

#define LOADB(ksv, sl) { \
    _Pragma("unroll") \
    for(int n=0;n<WCOLT;n++) bF[sl][n]=*(const short8*)(wp[n] + (size_t)(ksv)*512); }

  LOADA(0, 0); LOADB(0, 0); LOADB(1, 1);
  #pragma unroll
  for(int ks=0; ks<KSTEPS; ks++){
    if(ks+1<KSTEPS) LOADA(ks+1, (ks+1)&1);
    if(ks+2<KSTEPS) LOADB(ks+2, (ks+2)%3);
    #pragma unroll
    for(int m=0;m<ROWT;m++)
      #pragma unroll
      for(int n=0;n<WCOLT;n++)
        acc[m][n]=__builtin_amdgcn_mfma_f32_16x16x32_bf16(aF[ks&1][m],bF[ks%3][n],acc[m][n],0,0,0);
  }
#undef LOADA
#undef LOADB

  int g=bx&31;
  #pragma unroll
  for(int n=0;n<WCOLT;n++){
    float s=0,q=0;
    #pragma unroll
    for(int m=0;m<ROWT;m++)
      #pragma unroll
      for(int j=0;j<4;j++){ float a=acc[m][n][j]; s+=a; q+=a*a; }
    s += __shfl_xor(s,16); s += __shfl_xor(s,32);
    q += __shfl_xor(q,16); q += __shfl_xor(q,32);
    if(lhi==0){
      int o = colbase+n*16+l16;
      atomicAdd(&ws[spOut+g*512+o], s);
      atomicAdd(&ws[spOut+g*512+256+o], q);
    }
  }

  // epilogue: stage bf16 out-tile in LDS (reuse xs), coalesced uint4 copy-out
  __syncthreads();
  #pragma unroll
  for(int m=0;m<ROWT;m++)
    #pragma unroll
    for(int j=0;j<4;j++){
      int R = m*16 + lhi*4 + j;
      #pragma unroll
      for(int n=0;n<WCOLT;n++)
        xs[(size_t)R*OST + lcolbase + n*16 + l16] = f2bf(acc[m][n][j]);
    }
  __syncthreads();
  ushort* dst = yout + (size_t)eblk*M*OUT + (size_t)split*COLS;
  for(int idx=tid; idx<M*(COLS/8); idx+=256){
    int row = idx/(COLS/8), c8 = idx%(COLS/8);
    uint4 v = *(const uint4*)&xs[(size_t)row*OST + c8*8];
    *(uint4*)&dst[(size_t)row*OUT + c8*8] = v;
  }
}

// -------- fused pool+fc (C3 stats from partials) --------
__global__ __launch_bounds__(256) void k_poolfc(const float* __restrict__ fcw, float* __restrict__ ws){
  __shared__ float ps[16][260];
  __shared__ float red[4][32];
  __shared__ float mo[256][2];
  int tid=threadIdx.x;
  {
    float s=0,q=0;
    #pragma unroll
    for(int g=0;g<32;g++){ s+=ws[SP_C3+g*512+tid]; q+=ws[SP_C3+g*512+256+tid]; }
    float m=s*(1.0f/81920.0f);
    float v=q*(1.0f/81920.0f)-m*m; if(v<0)v=0;
    mo[tid][0]=m; mo[tid][1]=rsqrtf(v+EPSB);
  }
  __syncthreads();
  int e0=blockIdx.x*16;
  const ushort* y3=(const ushort*)(ws+F_Y13);
  float m=mo[tid][0], inv=mo[tid][1];
  for(int el=0;el<16;el++){
    const ushort* row=y3+((size_t)(e0+el)*20)*256+tid;
    float s=0;
    #pragma unroll
    for(int l=0;l<20;l++){
      float x=(bf2f(row[(size_t)l*256])-m)*inv;
      s += x>=0.f? x : 0.01f*x;
    }
    ps[el][tid]=s*(1.0f/20.0f);
  }
  __syncthreads();
  int e=tid>>4, h=tid&15;
  const float* wr=fcw+(size_t)h*256;
  float z=0;
  for(int c=0;c<256;c++) z+=ps[e][c]*wr[c];
  ws[F_FCB+(size_t)(e0+e)*16+h]=z;
  float s=z, q=z*z;
  #pragma unroll
  for(int o=16;o<64;o<<=1){ s+=__shfl_down(s,o); q+=__shfl_down(q,o); }
  int lane=tid&63, wid=tid>>6;
  if(lane<16){ red[wid][lane]=s; red[wid][16+lane]=q; }
  __syncthreads();
  if(tid<32){
    float v=red[0][tid]+red[1][tid]+red[2][tid]+red[3][tid];
    atomicAdd(&ws[tid<16? SO_FC+tid : SO_FCQ+(tid-16)], v);
  }
}

// -------- fused ef + edgeconv layer1: grid 128, 32 edges/block --------
__device__ __constant__ int EF_BASES[4][2] = {
  {SO_ET2,SO_ET2Q},{SO_EL2,SO_EL2Q},{SO_EV2,SO_EV2Q},{SO_FC,SO_FCQ}
};

__global__ __launch_bounds__(256) void k_aggef(const int* __restrict__ src, const int* __restrict__ dst,
    const float* __restrict__ ecW1, float* __restrict__ ws){
  __shared__ float w1s[64*17];
  __shared__ float mi[4][16][2];
  __shared__ float aLDS[32][17];
  __shared__ float zLDS[64][33];
  __shared__ float reds[4][64], redq[4][64];
  int tid=threadIdx.x;
  for(int i=tid;i<1024;i+=256) w1s[(i>>4)*17+(i&15)]=ecW1[i];
  if(tid<64){
    int g=tid>>4, h=tid&15;
    float m=ws[EF_BASES[g][0]+h]*(1.0f/4096.0f);
    float v=ws[EF_BASES[g][1]+h]*(1.0f/4096.0f)-m*m; if(v<0)v=0;
    mi[g][h][0]=m; mi[g][h][1]=rsqrtf(v+EPSB);
  }
  __syncthreads();
  int e0=blockIdx.x*32;
  for(int it=tid; it<32*16; it+=256){
    int el=it>>4, h=it&15;
    int e=e0+el;
    float z=ws[F_FCB+(size_t)e*16+h];
    float a=(z-mi[3][h][0])*mi[3][h][1];
    #pragma unroll
    for(int g=0;g<3;g++){
      float z2=ws[F_Z2T+(size_t)g*65536+(size_t)e*16+h];
      float r=(z2-mi[g][h][0])*mi[g][h][1];
      a+= r>0?r:0;
    }
    int s=src[e], d=dst[e];
    a+=ws[F_PROJ+(size_t)s*16+h]+ws[F_PROJ+(size_t)d*16+h];
    aLDS[el][h]=a;
  }
  __syncthreads();
  int o=tid&63, elq=tid>>6;
  float s=0,q=0;
  #pragma unroll
  for(int j=0;j<8;j++){
    int el=elq*8+j;
    float z=0;
    #pragma unroll
    for(int h=0;h<16;h++) z+=w1s[o*17+h]*aLDS[el][h];
    zLDS[o][el]=z;
    s+=z; q+=z*z;
  }
  reds[elq][o]=s; redq[elq][o]=q;
  __syncthreads();
  for(int idx=tid; idx<2048; idx+=256){
    int oo=idx>>5, el=idx&31;
    ws[F_Z1EC+(size_t)oo*E_+e0+el]=zLDS[oo][el];
  }
  if(tid<64){
    atomicAdd(&ws[SO_G1+tid], reds[0][tid]+reds[1][tid]+reds[2][tid]+reds[3][tid]);
  } else if(tid<128){
    int oo=tid-64;
    atomicAdd(&ws[SO_G1Q+oo], redq[0][oo]+redq[1][oo]+redq[2][oo]+redq[3][oo]);
  }
}

// ---------------- edgeconv layer2 ----------------
__global__ __launch_bounds__(256) void k_ec2(const float* __restrict__ ecW2, float* __restrict__ ws){
  __shared__ float w2s[1024];
  __shared__ float mi[64][2];
  int tid=threadIdx.x;
  for(int i=tid;i<1024;i+=256) w2s[i]=ecW2[i];
  if(tid<64){
    float m=ws[SO_G1+tid]*(1.0f/4096.0f);
    float v=ws[SO_G1Q+tid]*(1.0f/4096.0f)-m*m; if(v<0)v=0;
    mi[tid][0]=m; mi[tid][1]=rsqrtf(v+EPSB);
  }
  __syncthreads();
  int el=tid&63, kq=tid>>6;
  int e=blockIdx.x*64+el;
  float acc[4]={0,0,0,0};
  #pragma unroll 8
  for(int o=0;o<64;o++){
    float z=ws[F_Z1EC+(size_t)o*E_+e];
    float h=(z-mi[o][0])*mi[o][1];
    h=h>0?h:0;
    #pragma unroll
    for(int j=0;j<4;j++) acc[j]+=w2s[(kq*4+j)*64+o]*h;
  }
  #pragma unroll
  for(int j=0;j<4;j++) ws[F_FCB+(size_t)e*16+kq*4+j]=acc[j];
  #pragma unroll
  for(int j=0;j<4;j++){
    float rs=waveSum(acc[j]);
    float rq=waveSum(acc[j]*acc[j]);
    if(el==0){
      atomicAdd(&ws[SO_G2+kq*4+j], rs);
      atomicAdd(&ws[SO_G2Q+kq*4+j], rq);
    }
  }
}

// -------- edge_feature + per-hop projection --------
__global__ __launch_bounds__(256) void k_ef2g(const float* __restrict__ edisw, float* __restrict__ ws){
  __shared__ float wd[1280];
  __shared__ float mi[16][2];
  int tid=threadIdx.x;
  for(int i=tid;i<1280;i+=256) wd[i]=edisw[i];
  if(tid<16){
    float m=ws[SO_G2+tid]*(1.0f/4096.0f);
    float va=ws[SO_G2Q+tid]*(1.0f/4096.0f)-m*m; if(va<0)va=0;
    mi[tid][0]=m; mi[tid][1]=rsqrtf(va+EPSB);
  }
  __syncthreads();
  int t=blockIdx.x*256+tid;
  if(t>=4*1025*5) return;
  int bp=t/5, d=t%5;
  int b=bp/1025, pos=bp%1025;
  float ef[16];
  if(pos<1024){
    int e=b*1024+pos;
    #pragma unroll
    for(int k=0;k<16;k++){
      float z=ws[F_FCB+(size_t)e*16+k];
      float v=(z-mi[k][0])*mi[k][1];
      ef[k]= v>0?v:0;
    }
  } else {
    #pragma unroll
    for(int k=0;k<16;k++) ef[k]=0;
  }
  float* g=ws+F_G+(size_t)bp*80+d*16;
  const float* wdd=wd+d*256;
  #pragma unroll
  for(int k=0;k<16;k++){
    float s=0;
    #pragma unroll
    for(int h=0;h<16;h++) s+=ef[h]*wdd[h*16+k];
    g[k]=s;
  }
}

// ---------------- main per-pair kernel ----------------
__global__ __launch_bounds__(256) void k_pair(const float* __restrict__ ab,
    const int* __restrict__ sd, const float* __restrict__ ang, const float* __restrict__ cen,
    const int* __restrict__ ep, const float* __restrict__ sdemb,
    const float* __restrict__ angW1, const float* __restrict__ angW2,
    const float* __restrict__ cenW1, const float* __restrict__ cenW2,
    const float* __restrict__ ws, float* __restrict__ out){
  __shared__ float cpa[16],cma[16],m2a[16],i2a[16];
  __shared__ float cpc[16],cmc[16],m2c[16],i2c[16];
  __shared__ float mv[4];
  int tid=threadIdx.x;
  if(tid==0){
    float s=ws[SO_ANGX], q=ws[SO_ANGX+1];
    float mu=s*(1.0f/262144.0f);
    float v=q*(1.0f/262144.0f)-mu*mu; if(v<0)v=0;
    mv[0]=mu; mv[1]=v;
    s=ws[SO_CENX]; q=ws[SO_CENX+1];
    mu=s*(1.0f/262144.0f);
    v=q*(1.0f/262144.0f)-mu*mu; if(v<0)v=0;
    mv[2]=mu; mv[3]=v;
  }
  __syncthreads();
  if(tid<32){
    int k=tid&15; bool isC = tid>=16;
    const float* W1=isC?cenW1:angW1; const float* W2=isC?cenW2:angW2;
    float var=isC?mv[3]:mv[1];
    float cp=0, cm=0;
    for(int h=0;h<16;h++){
      float w=W1[h];
      float A=w*rsqrtf(var*w*w+EPSB);
      float wk=W2[k*16+h];
      if(A>0) cp+=wk*A; else cm+=wk*A;
    }
    int mo = isC? SO_MOMC : SO_MOMA;
    float P=ws[mo], N=ws[mo+1], Pq=ws[mo+2], Nq=ws[mo+3];
    float mean=(cp*P+cm*N)*(1.0f/262144.0f);
    float e2=(cp*cp*Pq+cm*cm*Nq)*(1.0f/262144.0f);
    float v2=e2-mean*mean; if(v2<0)v2=0;
    float iv=rsqrtf(v2+EPSB);
    if(!isC){ cpa[k]=cp; cma[k]=cm; m2a[k]=mean; i2a[k]=iv; }
    else    { cpc[k]=cp; cmc[k]=cm; m2c[k]=mean; i2c[k]=iv; }
  }
  __syncthreads();
  int t=blockIdx.x*256+tid;            // b,i,j
  int b=t>>16, rem=t&65535, i=rem>>8, j=rem&255;
  int sdv=sd[t];
  float xa=ang[t], xc0=cen[t];
  float acc[16];
  const float* se=sdemb+(size_t)sdv*16;
  #pragma unroll
  for(int k=0;k<16;k++) acc[k]=se[k];
  { // angle (closed form)
    float dx=xa-mv[0];
    bool pos=dx>0.f;
    #pragma unroll
    for(int k=0;k<16;k++){
      float z=dx*(pos?cpa[k]:cma[k]);
      float r=(z-m2a[k])*i2a[k];
      acc[k]+= r>0?r:0;
    }
  }
  { // centroid (closed form)
    float dx=xc0-mv[2];
    bool pos=dx>0.f;
    #pragma unroll
    for(int k=0;k<16;k++){
      float z=dx*(pos?cpc[k]:cmc[k]);
      float r=(z-m2c[k])*i2c[k];
      acc[k]+= r>0?r:0;
    }
  }
  { // multi-hop edge bias via precomputed G
    int sdm = sdv==0 ? 1 : sdv;
    if(sdm>1) sdm-=1;
    if(sdm>5) sdm=5;
    float inv=1.0f/((float)sdm+1e-6f);
    float eb[16];
    #pragma unroll
    for(int k=0;k<16;k++) eb[k]=0;
    const float* G=ws+F_G;
    #pragma unroll
    for(int d=0;d<5;d++){
      int idx=ep[(size_t)t*5+d];
      const float4* g=(const float4*)(G+(size_t)(b*1025+idx)*80+d*16);
      float4 g0=g[0], g1=g[1], g2=g[2], g3=g[3];
      eb[0]+=g0.x; eb[1]+=g0.y; eb[2]+=g0.z; eb[3]+=g0.w;
      eb[4]+=g1.x; eb[5]+=g1.y; eb[6]+=g1.z; eb[7]+=g1.w;
      eb[8]+=g2.x; eb[9]+=g2.y; eb[10]+=g2.z; eb[11]+=g2.w;
      eb[12]+=g3.x; eb[13]+=g3.y; eb[14]+=g3.z; eb[15]+=g3.w;
    }
    #pragma unroll
    for(int k=0;k<16;k++) acc[k]+=eb[k]*inv;
  }
  float base2=2.0f*ab[(size_t)b*66049+(size_t)(i+1)*257+(j+1)];
  #pragma unroll
  for(int k=0;k<16;k++)
    out[(((size_t)b*16+k)*257+(i+1))*257+(j+1)]=acc[k]+base2;
}

// ---------------- borders ----------------
__global__ __launch_bounds__(256) void k_border(const float* __restrict__ ab,
    const float* __restrict__ virt, float* __restrict__ out){
  int t=blockIdx.x*256+threadIdx.x;
  if(t>=4*16*513) return;
  int idx=t%513, bh=t/513;
  int b=bh>>4, h=bh&15;
  float v=virt[h];
  if(idx<257){
    out[(((size_t)b*16+h)*257)*257+idx]=2.0f*ab[(size_t)b*66049+idx]+v;
  } else {
    int p=idx-256;
    out[(((size_t)b*16+h)*257+p)*257]=2.0f*ab[(size_t)b*66049+(size_t)p*257]+v;
  }
}

extern "C" void kernel_launch(void* const* d_in, const int* in_sizes, int n_in,
                              void* d_out, int out_size, void* d_ws, size_t ws_size,
                              hipStream_t stream) {
  const float* ab    =(const float*)d_in[0];
  const int*   sdist =(const int*)  d_in[1];
  const float* ang   =(const float*)d_in[2];
  const float* cen   =(const float*)d_in[3];
  const int*   ep    =(const int*)  d_in[4];
  const float* edata =(const float*)d_in[5];
  const float* etype =(const float*)d_in[6];
  const float* elen  =(const float*)d_in[7];
  const float* econv =(const float*)d_in[8];
  const int*   src   =(const int*)  d_in[10];
  const int*   dst   =(const int*)  d_in[11];
  const float* nf    =(const float*)d_in[12];
  const float* sdemb =(const float*)d_in[13];
  const float* virt  =(const float*)d_in[14];
  const float* angW1 =(const float*)d_in[15];
  const float* angW2 =(const float*)d_in[16];
  const float* cenW1 =(const float*)d_in[17];
  const float* cenW2 =(const float*)d_in[18];
  const float* etW1  =(const float*)d_in[19];
  const float* etW2  =(const float*)d_in[20];
  const float* elW1  =(const float*)d_in[21];
  const float* elW2  =(const float*)d_in[22];
  const float* evW1  =(const float*)d_in[23];
  const float* evW2  =(const float*)d_in[24];
  const float* c1w   =(const float*)d_in[25];
  const float* c2w   =(const float*)d_in[26];
  const float* c3w   =(const float*)d_in[27];
  const float* fcw   =(const float*)d_in[28];
  const float* edisw =(const float*)d_in[29];
  const float* ecWp  =(const float*)d_in[30];
  const float* ecW1  =(const float*)d_in[31];
  const float* ecW2  =(const float*)d_in[32];
  float* ws=(float*)d_ws;
  float* out=(float*)d_out;

  k_zero<<<(PSTATS_END+255)/256,256,0,stream>>>(ws);

  k_conv1<<<512,256,0,stream>>>(edata,c1w,ws);
  k_misc<<<848,256,0,stream>>>(c2w,c3w,nf,ecWp,ang,cen,
                               etype,elen,econv,etW1,elW1,evW1,ws);
  k_stats2<<<112,256,0,stream>>>(ang,cen,etype,elen,econv,
                                 etW1,etW2,elW1,elW2,evW1,evW2,ws);

  k_convmf<64,128,4,2><<<2048,256,0,stream>>>((const ushort*)(ws+F_Y13),(const ushort*)(ws+F_WT2),
                                              (ushort*)(ws+F_Y2),ws,SP_C1,SP_C2);
  k_convmf<128,256,4,2><<<2048,256,0,stream>>>((const ushort*)(ws+F_Y2),(const ushort*)(ws+F_WT3),
                                               (ushort*)(ws+F_Y13),ws,SP_C2,SP_C3);
  k_poolfc<<<256,256,0,stream>>>(fcw,ws);

  k_aggef<<<128,256,0,stream>>>(src,dst,ecW1,ws);
  k_ec2<<<64,256,0,stream>>>(ecW2,ws);
  k_ef2g<<<81,256,0,stream>>>(edisw,ws);

  k_pair<<<1024,256,0,stream>>>(ab,sdist,ang,cen,ep,sdemb,angW1,angW2,cenW1,cenW2,ws,out);
  k_border<<<129,256,0,stream>>>(ab,virt,out);
}